// Round 11
// baseline (368.514 us; speedup 1.0000x reference)
//
#include <hip/hip_runtime.h>
#include <hip/hip_bf16.h>
#include <math.h>

#define NEG_SLOPE 0.2f

__device__ __forceinline__ unsigned short f2bf(float f) {
    unsigned int u = __float_as_uint(f);
    u = (u + 0x7fffu + ((u >> 16) & 1u)) >> 16;      // round-to-nearest-even
    return (unsigned short)u;
}
__device__ __forceinline__ float bflo(unsigned int p) {
    return __uint_as_float(p << 16);
}
__device__ __forceinline__ float bfhi(unsigned int p) {
    return __uint_as_float(p & 0xffff0000u);
}

// ---------------- GEMM + alpha body ----------------------------------------
// 32 rows per block, 256 threads. Thread t: row-group rg = t>>5 (rows
// rg, rg+8, rg+16, rg+24), col lane c = t&31 (cols 4c..4c+3, head c>>3).
__device__ __forceinline__ void gemm_alpha_body(
    float* __restrict__ xt,
    const float* __restrict__ X, const float* __restrict__ W,
    const float* __restrict__ a_src, const float* __restrict__ a_dst,
    unsigned short* __restrict__ Hb, float* __restrict__ as_out,
    float* __restrict__ ad_out, int N, int n0, int t)
{
    {
        const float4* src = (const float4*)(X + (size_t)n0 * 128);
        float4* dst = (float4*)xt;
        int rows = N - n0; if (rows > 32) rows = 32;
        int maxv = rows * 32;
        #pragma unroll
        for (int i = 0; i < 4; ++i) {
            int idx = t + i * 256;
            int g = idx < maxv ? idx : maxv - 1;
            dst[idx] = src[g];
        }
    }
    __syncthreads();

    int rg = t >> 5;
    int c  = t & 31;
    int j0 = c * 4;

    float a00=0.f,a01=0.f,a02=0.f,a03=0.f;
    float a10=0.f,a11=0.f,a12=0.f,a13=0.f;
    float a20=0.f,a21=0.f,a22=0.f,a23=0.f;
    float a30=0.f,a31=0.f,a32=0.f,a33=0.f;

    #pragma unroll 4
    for (int k = 0; k < 128; ++k) {
        float4 w = *(const float4*)(W + k * 128 + j0);
        float x0 = xt[(rg     ) * 128 + k];
        float x1 = xt[(rg +  8) * 128 + k];
        float x2 = xt[(rg + 16) * 128 + k];
        float x3 = xt[(rg + 24) * 128 + k];
        a00 = fmaf(x0, w.x, a00); a01 = fmaf(x0, w.y, a01);
        a02 = fmaf(x0, w.z, a02); a03 = fmaf(x0, w.w, a03);
        a10 = fmaf(x1, w.x, a10); a11 = fmaf(x1, w.y, a11);
        a12 = fmaf(x1, w.z, a12); a13 = fmaf(x1, w.w, a13);
        a20 = fmaf(x2, w.x, a20); a21 = fmaf(x2, w.y, a21);
        a22 = fmaf(x2, w.z, a22); a23 = fmaf(x2, w.w, a23);
        a30 = fmaf(x3, w.x, a30); a31 = fmaf(x3, w.y, a31);
        a32 = fmaf(x3, w.z, a32); a33 = fmaf(x3, w.w, a33);
    }

    float4 asv = *(const float4*)(a_src + j0);
    float4 adv = *(const float4*)(a_dst + j0);
    int head = c >> 3;
    int wlane = (c & 7) == 0;

    #pragma unroll
    for (int rr = 0; rr < 4; ++rr) {
        float b0, b1, b2, b3;
        if (rr == 0) { b0=a00; b1=a01; b2=a02; b3=a03; }
        else if (rr == 1) { b0=a10; b1=a11; b2=a12; b3=a13; }
        else if (rr == 2) { b0=a20; b1=a21; b2=a22; b3=a23; }
        else { b0=a30; b1=a31; b2=a32; b3=a33; }
        int row = n0 + rg + rr * 8;
        bool valid = row < N;
        if (valid) {
            unsigned int lo = (unsigned int)f2bf(b0) | ((unsigned int)f2bf(b1) << 16);
            unsigned int hi = (unsigned int)f2bf(b2) | ((unsigned int)f2bf(b3) << 16);
            *(uint2*)(Hb + (size_t)row * 128 + j0) = make_uint2(lo, hi);
        }
        float ps = b0*asv.x + b1*asv.y + b2*asv.z + b3*asv.w;
        float pd = b0*adv.x + b1*adv.y + b2*adv.z + b3*adv.w;
        ps += __shfl_xor(ps, 1, 64); pd += __shfl_xor(pd, 1, 64);
        ps += __shfl_xor(ps, 2, 64); pd += __shfl_xor(pd, 2, 64);
        ps += __shfl_xor(ps, 4, 64); pd += __shfl_xor(pd, 4, 64);
        if (wlane && valid) {
            as_out[row * 4 + head] = ps;
            ad_out[row * 4 + head] = pd;
        }
    }
}

__global__ __launch_bounds__(256) void gemm_alpha_kernel(
    const float* __restrict__ X, const float* __restrict__ W,
    const float* __restrict__ a_src, const float* __restrict__ a_dst,
    unsigned short* __restrict__ Hb, float* __restrict__ as_out,
    float* __restrict__ ad_out, int N)
{
    __shared__ float xt[32 * 128];
    gemm_alpha_body(xt, X, W, a_src, a_dst, Hb, as_out, ad_out, N,
                    blockIdx.x * 32, threadIdx.x);
}

// ---- layer-1 GEMM interleaved with XCD-localized CSR fill ------------------
// Groups of 8 blocks alternate roles. Fill uses pos[] = final csr index per
// edge; residue r's csr window is [offs[rlo], offs[rhi]) (csr is dst-ordered),
// so the range check needs ONLY pos. Reads per edge: pos (seq); esrc only for
// in-range edges.
__global__ __launch_bounds__(256) void gemm_fill_kernel(
    const float* __restrict__ X, const float* __restrict__ W,
    const float* __restrict__ a_src, const float* __restrict__ a_dst,
    unsigned short* __restrict__ Hb, float* __restrict__ as_out,
    float* __restrict__ ad_out, int N,
    const int* __restrict__ esrc, int E, int Et,
    const int* __restrict__ offs, const int* __restrict__ pos,
    int* __restrict__ csr, int gemmBlocks, int NS)
{
    __shared__ float xt[32 * 128];
    int g  = blockIdx.x >> 3;
    int l8 = blockIdx.x & 7;
    if ((g & 1) == 0) {
        int gb = (g >> 1) * 8 + l8;
        if (gb < gemmBlocks)
            gemm_alpha_body(xt, X, W, a_src, a_dst, Hb, as_out, ad_out, N,
                            gb * 32, threadIdx.x);
    } else {
        int slice = g >> 1;
        if (slice >= NS) return;
        int rlo = (int)(((long long)N * l8) >> 3);
        int rhi = (int)(((long long)N * (l8 + 1)) >> 3);
        int csrLo = offs[rlo];
        int csrHi = (rhi < N) ? offs[rhi] : Et;
        int e0 = (int)((long long)Et * slice / NS);
        int e1 = (int)((long long)Et * (slice + 1) / NS);
        for (int e = e0 + threadIdx.x; e < e1; e += 256) {
            int p = pos[e];
            if (p >= csrLo && p < csrHi) {
                int s = (e < E) ? esrc[e] : (e - E);
                csr[p] = s;
            }
        }
    }
}

// ---------------- CSR build helpers -----------------------------------------
__global__ __launch_bounds__(256) void zero_int_kernel(int* __restrict__ p, int n)
{
    int i = blockIdx.x * 256 + threadIdx.x;
    if (i < n) p[i] = 0;
}

// count per-dst degree AND record each edge's rank within its dst
__global__ __launch_bounds__(256) void count_rank_kernel(
    const int* __restrict__ edst, int E, int Et,
    int* __restrict__ cnt, int* __restrict__ rank)
{
    int e = blockIdx.x * 256 + threadIdx.x;
    if (e >= Et) return;
    int d = (e < E) ? edst[e] : (e - E);
    rank[e] = atomicAdd(&cnt[d], 1);
}

// pos[e] = offs[dst(e)] + rank[e]   (in-place over rank)
__global__ __launch_bounds__(256) void pos_kernel(
    const int* __restrict__ edst, int E, int Et,
    const int* __restrict__ offs, int* __restrict__ rank)
{
    int e = blockIdx.x * 256 + threadIdx.x;
    if (e >= Et) return;
    int d = (e < E) ? edst[e] : (e - E);
    rank[e] = offs[d] + rank[e];
}

__global__ __launch_bounds__(256) void scan_block_kernel(
    const int* __restrict__ in, int* __restrict__ out,
    int* __restrict__ bsum, int n)
{
    __shared__ int sh[256];
    int i = blockIdx.x * 256 + threadIdx.x;
    int v = (i < n) ? in[i] : 0;
    sh[threadIdx.x] = v;
    __syncthreads();
    #pragma unroll
    for (int off = 1; off < 256; off <<= 1) {
        int t = 0;
        if (threadIdx.x >= off) t = sh[threadIdx.x - off];
        __syncthreads();
        if (threadIdx.x >= off) sh[threadIdx.x] += t;
        __syncthreads();
    }
    if (i < n) out[i] = sh[threadIdx.x] - v;
    if (threadIdx.x == 255) bsum[blockIdx.x] = sh[255];
}

__global__ __launch_bounds__(256) void scan_add_kernel(
    int* __restrict__ offs, const int* __restrict__ bsum, int n)
{
    int i = blockIdx.x * 256 + threadIdx.x;
    if (i < n) offs[i] += bsum[blockIdx.x];
}

// ---------------- fused softmax + gather + bias + relu ----------------------
// 16-lane group per dst node; 4 nodes/wave, 16 nodes/block. Lane q owns
// features 8q..8q+7 (head h=q>>2). Per 16-edge chunk: lane q owns edge q
// (softmax via 4-level 16-wide shuffle trees, online rescale); weights parked
// in LDS [kk][g][h] (conflict-free); feature loop: ONE uint4 (8 bf16) global
// load + 8 FMAs per edge per lane, 4 node-streams per wave in flight.
__global__ __launch_bounds__(256) void gat_fused_kernel(
    const unsigned short* __restrict__ Hb, const int* __restrict__ csr,
    const int* __restrict__ offs, const int* __restrict__ cnt,
    const float* __restrict__ as, const float* __restrict__ ad,
    const float* __restrict__ bias, float* __restrict__ out, int N)
{
    __shared__ float wtab[4 * 256];   // per wave: [kk(16)][g(4)][h(4)]
    __shared__ int   stab[4 * 64];    // per wave: [g(4)][kk(16)]

    int t = threadIdx.x;
    int wv = t >> 6;
    int g  = (t >> 4) & 3;
    int q  = t & 15;
    int d = blockIdx.x * 16 + (t >> 4);
    if (d >= N) return;
    int start = offs[d];
    int deg = cnt[d];
    float4 adv = *(const float4*)(ad + d * 4);
    int h = q >> 2;
    int f0 = q * 8;

    float m0 = -INFINITY, m1 = -INFINITY, m2 = -INFINITY, m3 = -INFINITY;
    float s0 = 0.f, s1 = 0.f, s2 = 0.f, s3 = 0.f;
    float acc0=0.f,acc1=0.f,acc2=0.f,acc3=0.f,acc4=0.f,acc5=0.f,acc6=0.f,acc7=0.f;

    const float* wbase = wtab + wv * 256 + g * 4 + h;
    const int*   sbase = stab + wv * 64 + g * 16;

    for (int c0 = 0; c0 < deg; c0 += 16) {
        int rem = deg - c0;
        int len = rem < 16 ? rem : 16;
        bool valid = q < len;
        int sidx = valid ? csr[start + c0 + q] : 0;
        float4 av = *(const float4*)(as + sidx * 4);
        float e0 = av.x + adv.x; e0 = e0 > 0.f ? e0 : NEG_SLOPE * e0;
        float e1 = av.y + adv.y; e1 = e1 > 0.f ? e1 : NEG_SLOPE * e1;
        float e2 = av.z + adv.z; e2 = e2 > 0.f ? e2 : NEG_SLOPE * e2;
        float e3 = av.w + adv.w; e3 = e3 > 0.f ? e3 : NEG_SLOPE * e3;
        if (!valid) { e0 = e1 = e2 = e3 = -INFINITY; }

        float c0m = e0, c1m = e1, c2m = e2, c3m = e3;
        #pragma unroll
        for (int off = 8; off; off >>= 1) {
            c0m = fmaxf(c0m, __shfl_xor(c0m, off, 64));
            c1m = fmaxf(c1m, __shfl_xor(c1m, off, 64));
            c2m = fmaxf(c2m, __shfl_xor(c2m, off, 64));
            c3m = fmaxf(c3m, __shfl_xor(c3m, off, 64));
        }
        float nm0 = fmaxf(m0, c0m), nm1 = fmaxf(m1, c1m);
        float nm2 = fmaxf(m2, c2m), nm3 = fmaxf(m3, c3m);
        float r0 = __expf(m0 - nm0), r1 = __expf(m1 - nm1);
        float r2 = __expf(m2 - nm2), r3 = __expf(m3 - nm3);
        m0 = nm0; m1 = nm1; m2 = nm2; m3 = nm3;

        float w0 = valid ? __expf(e0 - m0) : 0.f;
        float w1 = valid ? __expf(e1 - m1) : 0.f;
        float w2 = valid ? __expf(e2 - m2) : 0.f;
        float w3 = valid ? __expf(e3 - m3) : 0.f;

        float t0 = w0, t1 = w1, t2 = w2, t3 = w3;
        #pragma unroll
        for (int off = 8; off; off >>= 1) {
            t0 += __shfl_xor(t0, off, 64);
            t1 += __shfl_xor(t1, off, 64);
            t2 += __shfl_xor(t2, off, 64);
            t3 += __shfl_xor(t3, off, 64);
        }
        s0 = s0 * r0 + t0; s1 = s1 * r1 + t1;
        s2 = s2 * r2 + t2; s3 = s3 * r3 + t3;
        float rs = h == 0 ? r0 : (h == 1 ? r1 : (h == 2 ? r2 : r3));
        acc0 *= rs; acc1 *= rs; acc2 *= rs; acc3 *= rs;
        acc4 *= rs; acc5 *= rs; acc6 *= rs; acc7 *= rs;

        // write: lane (wv,g,q) -> edge q weights at [q][g][0..3]
        ((float4*)wtab)[wv * 64 + q * 4 + g] = make_float4(w0, w1, w2, w3);
        stab[wv * 64 + g * 16 + q] = sidx;

        int kk = 0;
        for (; kk + 4 <= len; kk += 4) {
            int sk0 = sbase[kk+0], sk1 = sbase[kk+1];
            int sk2 = sbase[kk+2], sk3 = sbase[kk+3];
            float wa = wbase[(kk+0)*16], wb = wbase[(kk+1)*16];
            float wc = wbase[(kk+2)*16], wd = wbase[(kk+3)*16];
            uint4 p0 = *(const uint4*)(Hb + (size_t)sk0 * 128 + f0);
            uint4 p1 = *(const uint4*)(Hb + (size_t)sk1 * 128 + f0);
            uint4 p2 = *(const uint4*)(Hb + (size_t)sk2 * 128 + f0);
            uint4 p3 = *(const uint4*)(Hb + (size_t)sk3 * 128 + f0);
            acc0 = fmaf(wa, bflo(p0.x), acc0); acc1 = fmaf(wa, bfhi(p0.x), acc1);
            acc2 = fmaf(wa, bflo(p0.y), acc2); acc3 = fmaf(wa, bfhi(p0.y), acc3);
            acc4 = fmaf(wa, bflo(p0.z), acc4); acc5 = fmaf(wa, bfhi(p0.z), acc5);
            acc6 = fmaf(wa, bflo(p0.w), acc6); acc7 = fmaf(wa, bfhi(p0.w), acc7);
            acc0 = fmaf(wb, bflo(p1.x), acc0); acc1 = fmaf(wb, bfhi(p1.x), acc1);
            acc2 = fmaf(wb, bflo(p1.y), acc2); acc3 = fmaf(wb, bfhi(p1.y), acc3);
            acc4 = fmaf(wb, bflo(p1.z), acc4); acc5 = fmaf(wb, bfhi(p1.z), acc5);
            acc6 = fmaf(wb, bflo(p1.w), acc6); acc7 = fmaf(wb, bfhi(p1.w), acc7);
            acc0 = fmaf(wc, bflo(p2.x), acc0); acc1 = fmaf(wc, bfhi(p2.x), acc1);
            acc2 = fmaf(wc, bflo(p2.y), acc2); acc3 = fmaf(wc, bfhi(p2.y), acc3);
            acc4 = fmaf(wc, bflo(p2.z), acc4); acc5 = fmaf(wc, bfhi(p2.z), acc5);
            acc6 = fmaf(wc, bflo(p2.w), acc6); acc7 = fmaf(wc, bfhi(p2.w), acc7);
            acc0 = fmaf(wd, bflo(p3.x), acc0); acc1 = fmaf(wd, bfhi(p3.x), acc1);
            acc2 = fmaf(wd, bflo(p3.y), acc2); acc3 = fmaf(wd, bfhi(p3.y), acc3);
            acc4 = fmaf(wd, bflo(p3.z), acc4); acc5 = fmaf(wd, bfhi(p3.z), acc5);
            acc6 = fmaf(wd, bflo(p3.w), acc6); acc7 = fmaf(wd, bfhi(p3.w), acc7);
        }
        for (; kk < len; ++kk) {
            int sk = sbase[kk];
            float wk = wbase[kk*16];
            uint4 p = *(const uint4*)(Hb + (size_t)sk * 128 + f0);
            acc0 = fmaf(wk, bflo(p.x), acc0); acc1 = fmaf(wk, bfhi(p.x), acc1);
            acc2 = fmaf(wk, bflo(p.y), acc2); acc3 = fmaf(wk, bfhi(p.y), acc3);
            acc4 = fmaf(wk, bflo(p.z), acc4); acc5 = fmaf(wk, bfhi(p.z), acc5);
            acc6 = fmaf(wk, bflo(p.w), acc6); acc7 = fmaf(wk, bfhi(p.w), acc7);
        }
    }

    float sh = h == 0 ? s0 : (h == 1 ? s1 : (h == 2 ? s2 : s3));
    float inv = 1.f / (sh + 1e-16f);
    float4 bA = *(const float4*)(bias + f0);
    float4 bB = *(const float4*)(bias + f0 + 4);
    float4 oA = make_float4(fmaxf(acc0 * inv + bA.x, 0.f),
                            fmaxf(acc1 * inv + bA.y, 0.f),
                            fmaxf(acc2 * inv + bA.z, 0.f),
                            fmaxf(acc3 * inv + bA.w, 0.f));
    float4 oB = make_float4(fmaxf(acc4 * inv + bB.x, 0.f),
                            fmaxf(acc5 * inv + bB.y, 0.f),
                            fmaxf(acc6 * inv + bB.z, 0.f),
                            fmaxf(acc7 * inv + bB.w, 0.f));
    *(float4*)(out + (size_t)d * 128 + f0)     = oA;
    *(float4*)(out + (size_t)d * 128 + f0 + 4) = oB;
}

// ---------------- classifier head -------------------------------------------
__global__ __launch_bounds__(256) void classifier_kernel(
    const float* __restrict__ X, const float* __restrict__ Wc1,
    const float* __restrict__ bc1, const float* __restrict__ Wc2,
    const float* __restrict__ bc2, float* __restrict__ out, int N)
{
    int n = blockIdx.x * 8 + (threadIdx.x >> 5);
    if (n >= N) return;
    int j = threadIdx.x & 31;
    const float* xrow = X + (size_t)n * 128;
    float acc = bc1[j];
    #pragma unroll 8
    for (int k = 0; k < 128; ++k)
        acc = fmaf(xrow[k], Wc1[k * 32 + j], acc);
    float y = acc * Wc2[j];
    #pragma unroll
    for (int off = 16; off; off >>= 1) y += __shfl_xor(y, off, 64);
    if (j == 0)
        out[n] = 1.0f / (1.0f + expf(-(y + bc2[0])));
}

extern "C" void kernel_launch(void* const* d_in, const int* in_sizes, int n_in,
                              void* d_out, int out_size, void* d_ws, size_t ws_size,
                              hipStream_t stream)
{
    const float* x      = (const float*)d_in[0];
    const int*   eidx   = (const int*)d_in[1];
    const float* W1     = (const float*)d_in[2];
    const float* a_src1 = (const float*)d_in[3];
    const float* a_dst1 = (const float*)d_in[4];
    const float* b1     = (const float*)d_in[5];
    const float* W2     = (const float*)d_in[6];
    const float* a_src2 = (const float*)d_in[7];
    const float* a_dst2 = (const float*)d_in[8];
    const float* b2     = (const float*)d_in[9];
    const float* Wc1    = (const float*)d_in[10];
    const float* bc1    = (const float*)d_in[11];
    const float* Wc2    = (const float*)d_in[12];
    const float* bc2    = (const float*)d_in[13];

    int N  = in_sizes[0] / 128;
    int E  = in_sizes[1] / 2;
    int Et = E + N;
    const int* esrc = eidx;
    const int* edst = eidx + E;

    char* wsb = (char*)d_ws;
    unsigned short* Hb = (unsigned short*)wsb;  wsb += (size_t)N * 128 * 2;
    float*  f1_buf = (float*)wsb;   wsb += (size_t)N * 128 * 4;
    float*  as_buf = (float*)wsb;   wsb += (size_t)N * 4 * 4;
    float*  ad_buf = (float*)wsb;   wsb += (size_t)N * 4 * 4;
    int*    cnt    = (int*)wsb;     wsb += (size_t)N * 4;
    int*    offs   = (int*)wsb;     wsb += (size_t)N * 4;
    int*    bsum   = (int*)wsb;     wsb += 512 * 4;
    int*    csr    = (int*)wsb;     wsb += (size_t)Et * 4;
    int*    rank   = (int*)wsb;     wsb += (size_t)Et * 4;   // becomes pos[]

    int nbN = (N + 255) / 256;
    int nbE = (Et + 255) / 256;
    int gemmBlocks = (N + 31) / 32;
    int gemmGroups = (gemmBlocks + 7) / 8;
    int NS = gemmGroups;                       // fill slices (one odd group each)
    int fusedGrid = gemmGroups * 2 * 8;

    // ---- CSR count/scan/pos (shared by both layers) ----
    zero_int_kernel<<<nbN, 256, 0, stream>>>(cnt, N);
    count_rank_kernel<<<nbE, 256, 0, stream>>>(edst, E, Et, cnt, rank);
    scan_block_kernel<<<nbN, 256, 0, stream>>>(cnt, offs, bsum, N);
    scan_block_kernel<<<1, 256, 0, stream>>>(bsum, bsum, &bsum[300], nbN);
    scan_add_kernel<<<nbN, 256, 0, stream>>>(offs, bsum, N);
    pos_kernel<<<nbE, 256, 0, stream>>>(edst, E, Et, offs, rank);

    // ---- layer 1 GEMM interleaved with XCD-localized fill ----
    gemm_fill_kernel<<<fusedGrid, 256, 0, stream>>>(
        x, W1, a_src1, a_dst1, Hb, as_buf, ad_buf, N,
        esrc, E, Et, offs, rank, csr, gemmBlocks, NS);
    gat_fused_kernel<<<(N + 15) / 16, 256, 0, stream>>>(Hb, csr, offs, cnt,
                                                        as_buf, ad_buf, b1, f1_buf, N);
    // ---- layer 2 ----
    gemm_alpha_kernel<<<gemmBlocks, 256, 0, stream>>>(f1_buf, W2, a_src2, a_dst2,
                                                      Hb, as_buf, ad_buf, N);
    gat_fused_kernel<<<(N + 15) / 16, 256, 0, stream>>>(Hb, csr, offs, cnt,
                                                        as_buf, ad_buf, b2, f1_buf, N);

    // ---- classifier head -> d_out [N] ----
    classifier_kernel<<<(N + 7) / 8, 256, 0, stream>>>(f1_buf, Wc1, bc1, Wc2, bc2,
                                                       (float*)d_out, N);
}

// Round 12
// 310.740 us; speedup vs baseline: 1.1859x; 1.1859x over previous
//
#include <hip/hip_runtime.h>
#include <hip/hip_bf16.h>
#include <math.h>

#define NEG_SLOPE 0.2f

__device__ __forceinline__ unsigned short f2bf(float f) {
    unsigned int u = __float_as_uint(f);
    u = (u + 0x7fffu + ((u >> 16) & 1u)) >> 16;      // round-to-nearest-even
    return (unsigned short)u;
}
__device__ __forceinline__ float bflo(unsigned int p) {
    return __uint_as_float(p << 16);
}
__device__ __forceinline__ float bfhi(unsigned int p) {
    return __uint_as_float(p & 0xffff0000u);
}

// ---------------- GEMM + alpha: 64 rows/block, 256 threads ------------------
// Thread t: rg = t>>5 (rows rg+8*rr, rr=0..7), c = t&31 (cols 4c..4c+3,
// head c>>3). X tile (32 KB) in LDS. Per k: 1 W float4 + 8 LDS broadcasts +
// 32 FMA -> 2x FMA per W-byte vs 32-row version.
__global__ __launch_bounds__(256) void gemm_alpha_kernel(
    const float* __restrict__ X, const float* __restrict__ W,
    const float* __restrict__ a_src, const float* __restrict__ a_dst,
    unsigned short* __restrict__ Hb, float* __restrict__ as_out,
    float* __restrict__ ad_out, int N)
{
    __shared__ float xt[64 * 128];
    int n0 = blockIdx.x * 64;
    int t  = threadIdx.x;

    {
        const float4* src = (const float4*)(X + (size_t)n0 * 128);
        float4* dst = (float4*)xt;
        int rows = N - n0; if (rows > 64) rows = 64;
        int maxv = rows * 32;
        #pragma unroll
        for (int i = 0; i < 8; ++i) {
            int idx = t + i * 256;
            int g = idx < maxv ? idx : maxv - 1;
            dst[idx] = src[g];
        }
    }
    __syncthreads();

    int rg = t >> 5;
    int c  = t & 31;
    int j0 = c * 4;

    float acc[8][4];
    #pragma unroll
    for (int rr = 0; rr < 8; ++rr)
        { acc[rr][0]=0.f; acc[rr][1]=0.f; acc[rr][2]=0.f; acc[rr][3]=0.f; }

    #pragma unroll 2
    for (int k = 0; k < 128; ++k) {
        float4 w = *(const float4*)(W + k * 128 + j0);
        #pragma unroll
        for (int rr = 0; rr < 8; ++rr) {
            float xv = xt[(rg + rr * 8) * 128 + k];
            acc[rr][0] = fmaf(xv, w.x, acc[rr][0]);
            acc[rr][1] = fmaf(xv, w.y, acc[rr][1]);
            acc[rr][2] = fmaf(xv, w.z, acc[rr][2]);
            acc[rr][3] = fmaf(xv, w.w, acc[rr][3]);
        }
    }

    float4 asv = *(const float4*)(a_src + j0);
    float4 adv = *(const float4*)(a_dst + j0);
    int head = c >> 3;
    int wlane = (c & 7) == 0;

    #pragma unroll
    for (int rr = 0; rr < 8; ++rr) {
        float b0 = acc[rr][0], b1 = acc[rr][1], b2 = acc[rr][2], b3 = acc[rr][3];
        int row = n0 + rg + rr * 8;
        bool valid = row < N;
        if (valid) {
            unsigned int lo = (unsigned int)f2bf(b0) | ((unsigned int)f2bf(b1) << 16);
            unsigned int hi = (unsigned int)f2bf(b2) | ((unsigned int)f2bf(b3) << 16);
            *(uint2*)(Hb + (size_t)row * 128 + j0) = make_uint2(lo, hi);
        }
        float ps = b0*asv.x + b1*asv.y + b2*asv.z + b3*asv.w;
        float pd = b0*adv.x + b1*adv.y + b2*adv.z + b3*adv.w;
        ps += __shfl_xor(ps, 1, 64); pd += __shfl_xor(pd, 1, 64);
        ps += __shfl_xor(ps, 2, 64); pd += __shfl_xor(pd, 2, 64);
        ps += __shfl_xor(ps, 4, 64); pd += __shfl_xor(pd, 4, 64);
        if (wlane && valid) {
            as_out[row * 4 + head] = ps;
            ad_out[row * 4 + head] = pd;
        }
    }
}

// ---------------- CSR build helpers -----------------------------------------
__global__ __launch_bounds__(256) void zero_int_kernel(int* __restrict__ p, int n)
{
    int i = blockIdx.x * 256 + threadIdx.x;
    if (i < n) p[i] = 0;
}

__global__ __launch_bounds__(256) void count_rank_kernel(
    const int* __restrict__ edst, int E, int Et,
    int* __restrict__ cnt, int* __restrict__ rank)
{
    int e = blockIdx.x * 256 + threadIdx.x;
    if (e >= Et) return;
    int d = (e < E) ? edst[e] : (e - E);
    rank[e] = atomicAdd(&cnt[d], 1);
}

// pos[e] = offs[dst(e)] + rank[e]   (in-place over rank)
__global__ __launch_bounds__(256) void pos_kernel(
    const int* __restrict__ edst, int E, int Et,
    const int* __restrict__ offs, int* __restrict__ rank)
{
    int e = blockIdx.x * 256 + threadIdx.x;
    if (e >= Et) return;
    int d = (e < E) ? edst[e] : (e - E);
    rank[e] = offs[d] + rank[e];
}

__global__ __launch_bounds__(256) void scan_block_kernel(
    const int* __restrict__ in, int* __restrict__ out,
    int* __restrict__ bsum, int n)
{
    __shared__ int sh[256];
    int i = blockIdx.x * 256 + threadIdx.x;
    int v = (i < n) ? in[i] : 0;
    sh[threadIdx.x] = v;
    __syncthreads();
    #pragma unroll
    for (int off = 1; off < 256; off <<= 1) {
        int t = 0;
        if (threadIdx.x >= off) t = sh[threadIdx.x - off];
        __syncthreads();
        if (threadIdx.x >= off) sh[threadIdx.x] += t;
        __syncthreads();
    }
    if (i < n) out[i] = sh[threadIdx.x] - v;
    if (threadIdx.x == 255) bsum[blockIdx.x] = sh[255];
}

__global__ __launch_bounds__(256) void scan_add_kernel(
    int* __restrict__ offs, const int* __restrict__ bsum, int n)
{
    int i = blockIdx.x * 256 + threadIdx.x;
    if (i < n) offs[i] += bsum[blockIdx.x];
}

// ---- XCD-localized CSR fill (standalone). blockIdx&7 = residue r -> this
// block only writes csr positions inside residue r's dst-range window
// (~425 KB, L2-resident on one XCD under b%8 round-robin); slice = blockIdx>>3
// picks the edge-list portion. Reads: pos (seq, 8x re-read L3-served); esrc
// only for in-window edges.
__global__ __launch_bounds__(256) void fill_kernel(
    const int* __restrict__ esrc, int E, int Et, int N,
    const int* __restrict__ offs, const int* __restrict__ pos,
    int* __restrict__ csr, int S)
{
    int slice = blockIdx.x >> 3;
    int l8 = blockIdx.x & 7;
    if (slice >= S) return;
    int rlo = (int)(((long long)N * l8) >> 3);
    int rhi = (int)(((long long)N * (l8 + 1)) >> 3);
    int csrLo = offs[rlo];
    int csrHi = (rhi < N) ? offs[rhi] : Et;
    int e0 = (int)((long long)Et * slice / S);
    int e1 = (int)((long long)Et * (slice + 1) / S);
    for (int e = e0 + threadIdx.x; e < e1; e += 256) {
        int p = pos[e];
        if (p >= csrLo && p < csrHi)
            csr[p] = (e < E) ? esrc[e] : (e - E);
    }
}

// ---- collapsed classifier vector: v[i] = sum_j Wc1[i][j]*Wc2[j];
//      v[128] = bc1.Wc2 + bc2   (classifier is linear-linear -> one dot)
__global__ __launch_bounds__(128) void cls_vec_kernel(
    const float* __restrict__ Wc1, const float* __restrict__ bc1,
    const float* __restrict__ Wc2, const float* __restrict__ bc2,
    float* __restrict__ v)
{
    int i = threadIdx.x;
    float acc = 0.f;
    #pragma unroll
    for (int j = 0; j < 32; ++j)
        acc = fmaf(Wc1[i * 32 + j], Wc2[j], acc);
    v[i] = acc;
    if (i == 0) {
        float c = bc2[0];
        for (int j = 0; j < 32; ++j)
            c = fmaf(bc1[j], Wc2[j], c);
        v[128] = c;
    }
}

// ---------------- fused softmax + gather + bias + relu (+opt classifier) ----
// 16-lane group per dst node; 4 nodes/wave, 16 nodes/block. Lane q owns
// features 8q..8q+7 (head h=q>>2). docls: instead of storing the 128-f row,
// dot with v and write sigmoid scalar (layer 2).
__global__ __launch_bounds__(256) void gat_fused_kernel(
    const unsigned short* __restrict__ Hb, const int* __restrict__ csr,
    const int* __restrict__ offs, const int* __restrict__ cnt,
    const float* __restrict__ as, const float* __restrict__ ad,
    const float* __restrict__ bias, float* __restrict__ out, int N,
    const float* __restrict__ v, float* __restrict__ dcls, int docls)
{
    __shared__ float wtab[4 * 256];   // per wave: [kk(16)][g(4)][h(4)]
    __shared__ int   stab[4 * 64];    // per wave: [g(4)][kk(16)]

    int t = threadIdx.x;
    int wv = t >> 6;
    int g  = (t >> 4) & 3;
    int q  = t & 15;
    int d = blockIdx.x * 16 + (t >> 4);
    if (d >= N) return;
    int start = offs[d];
    int deg = cnt[d];
    float4 adv = *(const float4*)(ad + d * 4);
    int h = q >> 2;
    int f0 = q * 8;

    float m0 = -INFINITY, m1 = -INFINITY, m2 = -INFINITY, m3 = -INFINITY;
    float s0 = 0.f, s1 = 0.f, s2 = 0.f, s3 = 0.f;
    float acc0=0.f,acc1=0.f,acc2=0.f,acc3=0.f,acc4=0.f,acc5=0.f,acc6=0.f,acc7=0.f;

    const float* wbase = wtab + wv * 256 + g * 4 + h;
    const int*   sbase = stab + wv * 64 + g * 16;

    for (int c0 = 0; c0 < deg; c0 += 16) {
        int rem = deg - c0;
        int len = rem < 16 ? rem : 16;
        bool valid = q < len;
        int sidx = valid ? csr[start + c0 + q] : 0;
        float4 av = *(const float4*)(as + sidx * 4);
        float e0 = av.x + adv.x; e0 = e0 > 0.f ? e0 : NEG_SLOPE * e0;
        float e1 = av.y + adv.y; e1 = e1 > 0.f ? e1 : NEG_SLOPE * e1;
        float e2 = av.z + adv.z; e2 = e2 > 0.f ? e2 : NEG_SLOPE * e2;
        float e3 = av.w + adv.w; e3 = e3 > 0.f ? e3 : NEG_SLOPE * e3;
        if (!valid) { e0 = e1 = e2 = e3 = -INFINITY; }

        float c0m = e0, c1m = e1, c2m = e2, c3m = e3;
        #pragma unroll
        for (int off = 8; off; off >>= 1) {
            c0m = fmaxf(c0m, __shfl_xor(c0m, off, 64));
            c1m = fmaxf(c1m, __shfl_xor(c1m, off, 64));
            c2m = fmaxf(c2m, __shfl_xor(c2m, off, 64));
            c3m = fmaxf(c3m, __shfl_xor(c3m, off, 64));
        }
        float nm0 = fmaxf(m0, c0m), nm1 = fmaxf(m1, c1m);
        float nm2 = fmaxf(m2, c2m), nm3 = fmaxf(m3, c3m);
        float r0 = __expf(m0 - nm0), r1 = __expf(m1 - nm1);
        float r2 = __expf(m2 - nm2), r3 = __expf(m3 - nm3);
        m0 = nm0; m1 = nm1; m2 = nm2; m3 = nm3;

        float w0 = valid ? __expf(e0 - m0) : 0.f;
        float w1 = valid ? __expf(e1 - m1) : 0.f;
        float w2 = valid ? __expf(e2 - m2) : 0.f;
        float w3 = valid ? __expf(e3 - m3) : 0.f;

        float t0 = w0, t1 = w1, t2 = w2, t3 = w3;
        #pragma unroll
        for (int off = 8; off; off >>= 1) {
            t0 += __shfl_xor(t0, off, 64);
            t1 += __shfl_xor(t1, off, 64);
            t2 += __shfl_xor(t2, off, 64);
            t3 += __shfl_xor(t3, off, 64);
        }
        s0 = s0 * r0 + t0; s1 = s1 * r1 + t1;
        s2 = s2 * r2 + t2; s3 = s3 * r3 + t3;
        float rs = h == 0 ? r0 : (h == 1 ? r1 : (h == 2 ? r2 : r3));
        acc0 *= rs; acc1 *= rs; acc2 *= rs; acc3 *= rs;
        acc4 *= rs; acc5 *= rs; acc6 *= rs; acc7 *= rs;

        ((float4*)wtab)[wv * 64 + q * 4 + g] = make_float4(w0, w1, w2, w3);
        stab[wv * 64 + g * 16 + q] = sidx;

        int kk = 0;
        for (; kk + 4 <= len; kk += 4) {
            int sk0 = sbase[kk+0], sk1 = sbase[kk+1];
            int sk2 = sbase[kk+2], sk3 = sbase[kk+3];
            float wa = wbase[(kk+0)*16], wb = wbase[(kk+1)*16];
            float wc = wbase[(kk+2)*16], wd = wbase[(kk+3)*16];
            uint4 p0 = *(const uint4*)(Hb + (size_t)sk0 * 128 + f0);
            uint4 p1 = *(const uint4*)(Hb + (size_t)sk1 * 128 + f0);
            uint4 p2 = *(const uint4*)(Hb + (size_t)sk2 * 128 + f0);
            uint4 p3 = *(const uint4*)(Hb + (size_t)sk3 * 128 + f0);
            acc0 = fmaf(wa, bflo(p0.x), acc0); acc1 = fmaf(wa, bfhi(p0.x), acc1);
            acc2 = fmaf(wa, bflo(p0.y), acc2); acc3 = fmaf(wa, bfhi(p0.y), acc3);
            acc4 = fmaf(wa, bflo(p0.z), acc4); acc5 = fmaf(wa, bfhi(p0.z), acc5);
            acc6 = fmaf(wa, bflo(p0.w), acc6); acc7 = fmaf(wa, bfhi(p0.w), acc7);
            acc0 = fmaf(wb, bflo(p1.x), acc0); acc1 = fmaf(wb, bfhi(p1.x), acc1);
            acc2 = fmaf(wb, bflo(p1.y), acc2); acc3 = fmaf(wb, bfhi(p1.y), acc3);
            acc4 = fmaf(wb, bflo(p1.z), acc4); acc5 = fmaf(wb, bfhi(p1.z), acc5);
            acc6 = fmaf(wb, bflo(p1.w), acc6); acc7 = fmaf(wb, bfhi(p1.w), acc7);
            acc0 = fmaf(wc, bflo(p2.x), acc0); acc1 = fmaf(wc, bfhi(p2.x), acc1);
            acc2 = fmaf(wc, bflo(p2.y), acc2); acc3 = fmaf(wc, bfhi(p2.y), acc3);
            acc4 = fmaf(wc, bflo(p2.z), acc4); acc5 = fmaf(wc, bfhi(p2.z), acc5);
            acc6 = fmaf(wc, bflo(p2.w), acc6); acc7 = fmaf(wc, bfhi(p2.w), acc7);
            acc0 = fmaf(wd, bflo(p3.x), acc0); acc1 = fmaf(wd, bfhi(p3.x), acc1);
            acc2 = fmaf(wd, bflo(p3.y), acc2); acc3 = fmaf(wd, bfhi(p3.y), acc3);
            acc4 = fmaf(wd, bflo(p3.z), acc4); acc5 = fmaf(wd, bfhi(p3.z), acc5);
            acc6 = fmaf(wd, bflo(p3.w), acc6); acc7 = fmaf(wd, bfhi(p3.w), acc7);
        }
        for (; kk < len; ++kk) {
            int sk = sbase[kk];
            float wk = wbase[kk*16];
            uint4 p = *(const uint4*)(Hb + (size_t)sk * 128 + f0);
            acc0 = fmaf(wk, bflo(p.x), acc0); acc1 = fmaf(wk, bfhi(p.x), acc1);
            acc2 = fmaf(wk, bflo(p.y), acc2); acc3 = fmaf(wk, bfhi(p.y), acc3);
            acc4 = fmaf(wk, bflo(p.z), acc4); acc5 = fmaf(wk, bfhi(p.z), acc5);
            acc6 = fmaf(wk, bflo(p.w), acc6); acc7 = fmaf(wk, bfhi(p.w), acc7);
        }
    }

    float sh = h == 0 ? s0 : (h == 1 ? s1 : (h == 2 ? s2 : s3));
    float inv = 1.f / (sh + 1e-16f);
    float4 bA = *(const float4*)(bias + f0);
    float4 bB = *(const float4*)(bias + f0 + 4);
    float o0 = fmaxf(acc0 * inv + bA.x, 0.f);
    float o1 = fmaxf(acc1 * inv + bA.y, 0.f);
    float o2 = fmaxf(acc2 * inv + bA.z, 0.f);
    float o3 = fmaxf(acc3 * inv + bA.w, 0.f);
    float o4 = fmaxf(acc4 * inv + bB.x, 0.f);
    float o5 = fmaxf(acc5 * inv + bB.y, 0.f);
    float o6 = fmaxf(acc6 * inv + bB.z, 0.f);
    float o7 = fmaxf(acc7 * inv + bB.w, 0.f);

    if (!docls) {
        *(float4*)(out + (size_t)d * 128 + f0)     = make_float4(o0, o1, o2, o3);
        *(float4*)(out + (size_t)d * 128 + f0 + 4) = make_float4(o4, o5, o6, o7);
    } else {
        float4 vA = *(const float4*)(v + f0);
        float4 vB = *(const float4*)(v + f0 + 4);
        float part = o0*vA.x + o1*vA.y + o2*vA.z + o3*vA.w
                   + o4*vB.x + o5*vB.y + o6*vB.z + o7*vB.w;
        part += __shfl_xor(part, 1, 64);
        part += __shfl_xor(part, 2, 64);
        part += __shfl_xor(part, 4, 64);
        part += __shfl_xor(part, 8, 64);
        if (q == 0)
            dcls[d] = 1.0f / (1.0f + __expf(-(part + v[128])));
    }
}

extern "C" void kernel_launch(void* const* d_in, const int* in_sizes, int n_in,
                              void* d_out, int out_size, void* d_ws, size_t ws_size,
                              hipStream_t stream)
{
    const float* x      = (const float*)d_in[0];
    const int*   eidx   = (const int*)d_in[1];
    const float* W1     = (const float*)d_in[2];
    const float* a_src1 = (const float*)d_in[3];
    const float* a_dst1 = (const float*)d_in[4];
    const float* b1     = (const float*)d_in[5];
    const float* W2     = (const float*)d_in[6];
    const float* a_src2 = (const float*)d_in[7];
    const float* a_dst2 = (const float*)d_in[8];
    const float* b2     = (const float*)d_in[9];
    const float* Wc1    = (const float*)d_in[10];
    const float* bc1    = (const float*)d_in[11];
    const float* Wc2    = (const float*)d_in[12];
    const float* bc2    = (const float*)d_in[13];

    int N  = in_sizes[0] / 128;
    int E  = in_sizes[1] / 2;
    int Et = E + N;
    const int* esrc = eidx;
    const int* edst = eidx + E;

    char* wsb = (char*)d_ws;
    unsigned short* Hb = (unsigned short*)wsb;  wsb += (size_t)N * 128 * 2;
    float*  f1_buf = (float*)wsb;   wsb += (size_t)N * 128 * 4;
    float*  as_buf = (float*)wsb;   wsb += (size_t)N * 4 * 4;
    float*  ad_buf = (float*)wsb;   wsb += (size_t)N * 4 * 4;
    int*    cnt    = (int*)wsb;     wsb += (size_t)N * 4;
    int*    offs   = (int*)wsb;     wsb += (size_t)N * 4;
    int*    bsum   = (int*)wsb;     wsb += 512 * 4;
    int*    csr    = (int*)wsb;     wsb += (size_t)Et * 4;
    int*    rank   = (int*)wsb;     wsb += (size_t)Et * 4;   // becomes pos[]
    float*  vcls   = (float*)wsb;   wsb += 132 * 4;

    int nbN = (N + 255) / 256;
    int nbE = (Et + 255) / 256;
    int gemmBlocks = (N + 63) / 64;
    int S = 512;                               // fill slices

    // ---- CSR count/scan/pos (shared by both layers) + classifier collapse --
    zero_int_kernel<<<nbN, 256, 0, stream>>>(cnt, N);
    count_rank_kernel<<<nbE, 256, 0, stream>>>(edst, E, Et, cnt, rank);
    scan_block_kernel<<<nbN, 256, 0, stream>>>(cnt, offs, bsum, N);
    scan_block_kernel<<<1, 256, 0, stream>>>(bsum, bsum, &bsum[300], nbN);
    scan_add_kernel<<<nbN, 256, 0, stream>>>(offs, bsum, N);
    pos_kernel<<<nbE, 256, 0, stream>>>(edst, E, Et, offs, rank);
    cls_vec_kernel<<<1, 128, 0, stream>>>(Wc1, bc1, Wc2, bc2, vcls);
    fill_kernel<<<S * 8, 256, 0, stream>>>(esrc, E, Et, N, offs, rank, csr, S);

    // ---- layer 1: x -> f1 ----
    gemm_alpha_kernel<<<gemmBlocks, 256, 0, stream>>>(x, W1, a_src1, a_dst1,
                                                      Hb, as_buf, ad_buf, N);
    gat_fused_kernel<<<(N + 15) / 16, 256, 0, stream>>>(Hb, csr, offs, cnt,
        as_buf, ad_buf, b1, f1_buf, N, vcls, (float*)d_out, 0);
    // ---- layer 2: f1 -> d_out (classifier fused into epilogue) ----
    gemm_alpha_kernel<<<gemmBlocks, 256, 0, stream>>>(f1_buf, W2, a_src2, a_dst2,
                                                      Hb, as_buf, ad_buf, N);
    gat_fused_kernel<<<(N + 15) / 16, 256, 0, stream>>>(Hb, csr, offs, cnt,
        as_buf, ad_buf, b2, f1_buf, N, vcls, (float*)d_out, 1);
}